// Round 9
// baseline (180.323 us; speedup 1.0000x reference)
//
#include <hip/hip_runtime.h>
#include <hip/hip_bf16.h>

// B=2048, T=128, H=48, L=3. Gates G=192.
// WG = 3 waves (192 thr) x 4 batches; 512 WGs (2/CU, both co-resident at
// VGPR<=256). Weights in registers. 3 barriers/step. 1 cell/lane: lane
// (c,kg,wv) owns cell (j=16wv+c, b=kg); M=16 rows duplicate the 4 batches
// 4x so acc element r = batch r in EVERY lane -> gate extraction is a
// 3-cndmask select (sel4), no LDS round-trip, scalar cell math.
// samp fold is scalar: u_k/vb_k preselected (loop-invariant).
//
// Mapping (validated R1-R8): A-frag lane(c,kg) = A[m=c][k=8kg..+7] per
// 32-wide ktile; B-frag = W[n][k0..+7], n = 48g+16wv+c; D elem r of lane
// (c,kg) = D[m=4kg+r][n=c], batch = m&3 = r.

using bf16x8 = __attribute__((ext_vector_type(8))) __bf16;
using u16x8  = __attribute__((ext_vector_type(8))) unsigned short;
using f32x4  = __attribute__((ext_vector_type(4))) float;

__device__ __forceinline__ float fexp2(float x){ return __builtin_amdgcn_exp2f(x); }
__device__ __forceinline__ float frcp (float x){ return __builtin_amdgcn_rcpf(x); }
__device__ __forceinline__ float sigm (float x){ return frcp(1.f + fexp2(-1.44269504f*x)); }
__device__ __forceinline__ float tanha(float x){ return 1.f - 2.f*frcp(1.f + fexp2(2.88539008f*x)); }

__device__ __forceinline__ unsigned short f2bf(float x){
  unsigned u = __float_as_uint(x);
  return (unsigned short)((u + 0x7FFFu + ((u>>16)&1u)) >> 16);  // RNE
}

__device__ __forceinline__ f32x4 mfma16(u16x8 a, u16x8 b, f32x4 c){
  return __builtin_amdgcn_mfma_f32_16x16x32_bf16(
      __builtin_bit_cast(bf16x8, a), __builtin_bit_cast(bf16x8, b), c, 0, 0, 0);
}

// element kg of a f32x4 acc, via cndmask tree (kg lane-varying, no scratch)
__device__ __forceinline__ float sel4(const f32x4& a, int kg){
  const float e01 = (kg & 1) ? a[1] : a[0];
  const float e23 = (kg & 1) ? a[3] : a[2];
  return (kg & 2) ? e23 : e01;
}

#define MM4(A, WK) \
  ac0 = mfma16(A, WK[0], ac0); ac1 = mfma16(A, WK[1], ac1); \
  ac2 = mfma16(A, WK[2], ac2); ac3 = mfma16(A, WK[3], ac3);

__global__ __launch_bounds__(192, 2) void lstm_fused(
    const float* __restrict__ adj, const float* __restrict__ eps,
    const float* __restrict__ Wi,  const float* __restrict__ bi,
    const float* __restrict__ Wa,  const float* __restrict__ ba,
    const float* __restrict__ Wp,  const float* __restrict__ bp,
    const float* __restrict__ Wih, const float* __restrict__ Whh,
    const float* __restrict__ bih, const float* __restrict__ bhh,
    const float* __restrict__ h0,  const float* __restrict__ c0,
    float* __restrict__ out)
{
  const int tid  = threadIdx.x;
  const int wv   = tid >> 6;          // 0..2
  const int lane = tid & 63;
  const int c    = lane & 15;
  const int kg   = lane >> 4;         // 0..3; owned batch = kg
  const int j    = 16*wv + c;         // owned hidden index
  const int b0   = blockIdx.x * 4;    // 4 batches per WG
  const int cr   = c & 3;             // A-row batch for frag reads

  __shared__ __align__(16) unsigned short hbuf[3][4][104]; // h_l; [48..63] = 0 pad
  __shared__ __align__(16) float adjT[128][4];
  __shared__ __align__(16) float epsT[128][4];
  __shared__ __align__(16) float outb[128][4];

  // ---- weight fragments -> registers ----
  u16x8 wf1[3][4], wf2[3][4];  // layers 1,2: [Wih|Whh], K=96
  u16x8 wf0[2][4], wfx[2][4];  // layer 0: Whh (K=48 pad 64); Wih (u/v passes)
  u16x8 wpf[2];                // Wp replicated across all 16 columns
  float biasr0[4], biasr1[4], biasr2[4];
#pragma unroll
  for (int kk = 0; kk < 3; ++kk) {
    const int k0 = 32*kk + 8*kg;
#pragma unroll
    for (int g = 0; g < 4; ++g) {
      const int n = 48*g + j;
#pragma unroll
      for (int l = 1; l < 3; ++l) {
        const float* src = (k0 < 48) ? (Wih + ((l*192 + n)*48 + k0))
                                     : (Whh + ((l*192 + n)*48 + (k0 - 48)));
        float4 p0 = *reinterpret_cast<const float4*>(src);
        float4 p1 = *reinterpret_cast<const float4*>(src + 4);
        u16x8 f;
        f[0]=f2bf(p0.x); f[1]=f2bf(p0.y); f[2]=f2bf(p0.z); f[3]=f2bf(p0.w);
        f[4]=f2bf(p1.x); f[5]=f2bf(p1.y); f[6]=f2bf(p1.z); f[7]=f2bf(p1.w);
        if (l == 1) wf1[kk][g] = f; else wf2[kk][g] = f;
      }
    }
  }
#pragma unroll
  for (int kk = 0; kk < 2; ++kk) {
    const int k0 = 32*kk + 8*kg;
#pragma unroll
    for (int g = 0; g < 4; ++g) {
      const int n = 48*g + j;
      u16x8 fh = {0,0,0,0,0,0,0,0}, fx = fh;
      if (k0 < 48) {
        const float* sh = Whh + (n*48 + k0);      // layer 0
        const float* sx = Wih + (n*48 + k0);
        float4 p0 = *reinterpret_cast<const float4*>(sh);
        float4 p1 = *reinterpret_cast<const float4*>(sh + 4);
        fh[0]=f2bf(p0.x); fh[1]=f2bf(p0.y); fh[2]=f2bf(p0.z); fh[3]=f2bf(p0.w);
        fh[4]=f2bf(p1.x); fh[5]=f2bf(p1.y); fh[6]=f2bf(p1.z); fh[7]=f2bf(p1.w);
        p0 = *reinterpret_cast<const float4*>(sx);
        p1 = *reinterpret_cast<const float4*>(sx + 4);
        fx[0]=f2bf(p0.x); fx[1]=f2bf(p0.y); fx[2]=f2bf(p0.z); fx[3]=f2bf(p0.w);
        fx[4]=f2bf(p1.x); fx[5]=f2bf(p1.y); fx[6]=f2bf(p1.z); fx[7]=f2bf(p1.w);
      }
      wf0[kk][g] = fh; wfx[kk][g] = fx;
    }
    u16x8 fp = {0,0,0,0,0,0,0,0};
#pragma unroll
    for (int e = 0; e < 8; ++e) {
      const int k = k0 + e;
      if (k < 48) fp[e] = f2bf(Wp[k]);
    }
    wpf[kk] = fp;
  }
#pragma unroll
  for (int g = 0; g < 4; ++g) {
    const int n = 48*g + j;
    biasr0[g] = bih[        n] + bhh[        n];
    biasr1[g] = bih[192   + n] + bhh[192   + n];
    biasr2[g] = bih[2*192 + n] + bhh[2*192 + n];
  }

  // ---- stage adj/eps transposed: [t][b] ----
  if (tid < 128) {
    const int b = tid >> 5, q = tid & 31;
    const float4 va = reinterpret_cast<const float4*>(adj + (size_t)(b0+b)*128)[q];
    adjT[4*q+0][b]=va.x; adjT[4*q+1][b]=va.y; adjT[4*q+2][b]=va.z; adjT[4*q+3][b]=va.w;
    const float4 ve = reinterpret_cast<const float4*>(eps + (size_t)(b0+b)*128)[q];
    epsT[4*q+0][b]=ve.x; epsT[4*q+1][b]=ve.y; epsT[4*q+2][b]=ve.z; epsT[4*q+3][b]=ve.w;
  }
  const float bp0 = bp[0];
  __syncthreads();

  // ---- adjemb -> A_u (hbuf[0]), A_v (hbuf[1]) [one (b,jj) per thread]; pads ----
  {
    const int b = tid & 3, jj = tid >> 2;
    float s = ba[jj];
    const float* wr = Wa + jj*128;
    for (int t2 = 0; t2 < 128; ++t2) s += adjT[t2][b] * wr[t2];
    hbuf[0][b][jj] = f2bf(Wi[jj] * s);
    hbuf[1][b][jj] = f2bf(bi[jj] * s);
    hbuf[wv][lane >> 4][48 + (lane & 15)] = 0;   // zero pads, all (l,b,48..63)
  }
  __syncthreads();

  // ---- u,v via MFMA passes; keep only element kg (loop-invariant scalars) ----
  float u_k[4], vb_k[4];
  {
    const f32x4 z4 = {0.f,0.f,0.f,0.f};
    const unsigned short* rp = &hbuf[0][cr][0];
    u16x8 A0 = *reinterpret_cast<const u16x8*>(rp + 8*kg);
    u16x8 A1 = *reinterpret_cast<const u16x8*>(rp + 32 + 8*kg);
#pragma unroll
    for (int g = 0; g < 4; ++g) {
      f32x4 u = mfma16(A1, wfx[1][g], mfma16(A0, wfx[0][g], z4));
      u_k[g] = sel4(u, kg);
    }
    rp = &hbuf[1][cr][0];
    A0 = *reinterpret_cast<const u16x8*>(rp + 8*kg);
    A1 = *reinterpret_cast<const u16x8*>(rp + 32 + 8*kg);
#pragma unroll
    for (int g = 0; g < 4; ++g) {
      f32x4 v = mfma16(A1, wfx[1][g], mfma16(A0, wfx[0][g], z4));
      vb_k[g] = sel4(v, kg) + biasr0[g];
    }
  }
  __syncthreads();   // u/v reads done before h-init overwrites

  // ---- h/c init ----
  for (int cid = tid; cid < 576; cid += 192) {
    const int l = cid / 192, r2 = cid % 192, b = r2 & 3, jj = r2 >> 2;
    hbuf[l][b][jj] = f2bf(h0[l*48 + jj]);
  }
  float cv0 = c0[j], cv1 = c0[48 + j], cv2 = c0[2*48 + j];
  __syncthreads();

  // ---- pre-loop hoisted L0: gacc = vb_k-splat + Whh0 @ h0(init) ----
  f32x4 g0, g1, g2, g3;
  {
    const unsigned short* rp = &hbuf[0][cr][0];
    const u16x8 A0 = *reinterpret_cast<const u16x8*>(rp + 8*kg);
    const u16x8 A1 = *reinterpret_cast<const u16x8*>(rp + 32 + 8*kg);
    g0 = (f32x4){vb_k[0], vb_k[0], vb_k[0], vb_k[0]};
    g1 = (f32x4){vb_k[1], vb_k[1], vb_k[1], vb_k[1]};
    g2 = (f32x4){vb_k[2], vb_k[2], vb_k[2], vb_k[2]};
    g3 = (f32x4){vb_k[3], vb_k[3], vb_k[3], vb_k[3]};
    g0 = mfma16(A0, wf0[0][0], g0); g1 = mfma16(A0, wf0[0][1], g1);
    g2 = mfma16(A0, wf0[0][2], g2); g3 = mfma16(A0, wf0[0][3], g3);
    g0 = mfma16(A1, wf0[1][0], g0); g1 = mfma16(A1, wf0[1][1], g1);
    g2 = mfma16(A1, wf0[1][2], g2); g3 = mfma16(A1, wf0[1][3], g3);
  }

  const f32x4 bp4 = {bp0, bp0, bp0, bp0};
  f32x4 avR = {0.f,0.f,0.f,0.f}, evR = avR;   // prefetched adj/eps row for samp

  for (int t = 0; t < 128; ++t) {
    // ---- samp(t-1): MFMA mean from h2(t-1); scalar select for own batch ----
    float s_kg = 0.f;
    if (t) {
      const u16x8 mh0 = *reinterpret_cast<const u16x8*>(&hbuf[2][cr][8*kg]);
      const u16x8 mh1 = *reinterpret_cast<const u16x8*>(&hbuf[2][cr][32 + 8*kg]);
      f32x4 mz = {0.f,0.f,0.f,0.f};
      mz = mfma16(mh0, wpf[0], mz);
      mz = mfma16(mh1, wpf[1], mz);
      const f32x4 sampv = (mz + bp4 + evR) * avR;
      if (tid == 0)
        *reinterpret_cast<f32x4*>(&outb[t-1][0]) = sampv;
      s_kg = sel4(sampv, kg);
    }
    // ---- L0 cell: scalar gates = sel4(acc) + samp*u ----
    {
      const float gi = sel4(g0, kg) + s_kg*u_k[0];
      const float gf = sel4(g1, kg) + s_kg*u_k[1];
      const float gg = sel4(g2, kg) + s_kg*u_k[2];
      const float go = sel4(g3, kg) + s_kg*u_k[3];
      const float cn = sigm(gf)*cv0 + sigm(gi)*tanha(gg);
      cv0 = cn;
      hbuf[0][kg][j] = f2bf(sigm(go)*tanha(cn));
    }
    // prefetch L1 old-h half (h1(t-1); next written after B1 -> safe)
    u16x8 a11 = {0,0,0,0,0,0,0,0}, a12;
    if (kg >= 2) a11 = *reinterpret_cast<const u16x8*>(&hbuf[1][cr][8*kg - 16]);
    a12 = *reinterpret_cast<const u16x8*>(&hbuf[1][cr][16 + 8*kg]);
    __syncthreads();   // B1: h0(t) visible
    // ---- L1 ----
    {
      const unsigned short* rp = &hbuf[0][cr][0];
      const u16x8 a10 = *reinterpret_cast<const u16x8*>(rp + 8*kg);
      if (kg < 2) a11 = *reinterpret_cast<const u16x8*>(rp + 32 + 8*kg);
      f32x4 ac0 = {biasr1[0], biasr1[0], biasr1[0], biasr1[0]};
      f32x4 ac1 = {biasr1[1], biasr1[1], biasr1[1], biasr1[1]};
      f32x4 ac2 = {biasr1[2], biasr1[2], biasr1[2], biasr1[2]};
      f32x4 ac3 = {biasr1[3], biasr1[3], biasr1[3], biasr1[3]};
      MM4(a12, wf1[2]);   // prefetched operand first
      MM4(a10, wf1[0]);
      MM4(a11, wf1[1]);
      const float gi = sel4(ac0, kg), gf = sel4(ac1, kg);
      const float gg = sel4(ac2, kg), go = sel4(ac3, kg);
      const float cn = sigm(gf)*cv1 + sigm(gi)*tanha(gg);
      cv1 = cn;
      hbuf[1][kg][j] = f2bf(sigm(go)*tanha(cn));
    }
    // prefetch L2 old-h half (h2(t-1); next written after B2 -> safe)
    u16x8 a21 = {0,0,0,0,0,0,0,0}, a22;
    if (kg >= 2) a21 = *reinterpret_cast<const u16x8*>(&hbuf[2][cr][8*kg - 16]);
    a22 = *reinterpret_cast<const u16x8*>(&hbuf[2][cr][16 + 8*kg]);
    __syncthreads();   // B2: h1(t) visible
    // ---- L2 + prefetches + hoisted L0 for t+1 ----
    {
      const unsigned short* rp = &hbuf[1][cr][0];
      const u16x8 a20 = *reinterpret_cast<const u16x8*>(rp + 8*kg);
      if (kg < 2) a21 = *reinterpret_cast<const u16x8*>(rp + 32 + 8*kg);
      // prefetch next-step L0 A-frags (h0(t): written pre-B1, overwritten post-B3)
      const unsigned short* rp0 = &hbuf[0][cr][0];
      const u16x8 a00 = *reinterpret_cast<const u16x8*>(rp0 + 8*kg);
      const u16x8 a01 = *reinterpret_cast<const u16x8*>(rp0 + 32 + 8*kg);
      // prefetch adj/eps row t (read-only) for samp(t) at next loop top
      avR = *reinterpret_cast<const f32x4*>(&adjT[t][0]);
      evR = *reinterpret_cast<const f32x4*>(&epsT[t][0]);
      f32x4 ac0 = {biasr2[0], biasr2[0], biasr2[0], biasr2[0]};
      f32x4 ac1 = {biasr2[1], biasr2[1], biasr2[1], biasr2[1]};
      f32x4 ac2 = {biasr2[2], biasr2[2], biasr2[2], biasr2[2]};
      f32x4 ac3 = {biasr2[3], biasr2[3], biasr2[3], biasr2[3]};
      MM4(a22, wf2[2]);
      MM4(a20, wf2[0]);
      MM4(a21, wf2[1]);
      const float gi = sel4(ac0, kg), gf = sel4(ac1, kg);
      const float gg = sel4(ac2, kg), go = sel4(ac3, kg);
      const float cn = sigm(gf)*cv2 + sigm(gi)*tanha(gg);
      cv2 = cn;
      hbuf[2][kg][j] = f2bf(sigm(go)*tanha(cn));
      // hoisted L0 base gates for step t+1
      g0 = (f32x4){vb_k[0], vb_k[0], vb_k[0], vb_k[0]};
      g1 = (f32x4){vb_k[1], vb_k[1], vb_k[1], vb_k[1]};
      g2 = (f32x4){vb_k[2], vb_k[2], vb_k[2], vb_k[2]};
      g3 = (f32x4){vb_k[3], vb_k[3], vb_k[3], vb_k[3]};
      g0 = mfma16(a00, wf0[0][0], g0); g1 = mfma16(a00, wf0[0][1], g1);
      g2 = mfma16(a00, wf0[0][2], g2); g3 = mfma16(a00, wf0[0][3], g3);
      g0 = mfma16(a01, wf0[1][0], g0); g1 = mfma16(a01, wf0[1][1], g1);
      g2 = mfma16(a01, wf0[1][2], g2); g3 = mfma16(a01, wf0[1][3], g3);
    }
    __syncthreads();   // B3: h2(t) + all h-writes settled
  }
  // ---- epilogue: samp(127) ----
  {
    const u16x8 mh0 = *reinterpret_cast<const u16x8*>(&hbuf[2][cr][8*kg]);
    const u16x8 mh1 = *reinterpret_cast<const u16x8*>(&hbuf[2][cr][32 + 8*kg]);
    f32x4 mz = {0.f,0.f,0.f,0.f};
    mz = mfma16(mh0, wpf[0], mz);
    mz = mfma16(mh1, wpf[1], mz);
    const f32x4 sv = (mz + bp4 + evR) * avR;   // avR/evR hold row 127
    if (tid == 0)
      *reinterpret_cast<f32x4*>(&outb[127][0]) = sv;
  }
  __syncthreads();
  // ---- final coalesced store ----
  for (int i = tid; i < 512; i += 192) {
    const int b = i >> 7, tt = i & 127;
    out[(size_t)(b0 + b)*128 + tt] = outb[tt][b];
  }
}

extern "C" void kernel_launch(void* const* d_in, const int* in_sizes, int n_in,
                              void* d_out, int out_size, void* d_ws, size_t ws_size,
                              hipStream_t stream) {
  const float* adj = (const float*)d_in[0];
  const float* eps = (const float*)d_in[1];
  const float* Wi  = (const float*)d_in[2];
  const float* bi  = (const float*)d_in[3];
  const float* Wa  = (const float*)d_in[4];
  const float* ba  = (const float*)d_in[5];
  const float* Wp  = (const float*)d_in[6];
  const float* bp  = (const float*)d_in[7];
  const float* Wih = (const float*)d_in[8];
  const float* Whh = (const float*)d_in[9];
  const float* bih = (const float*)d_in[10];
  const float* bhh = (const float*)d_in[11];
  const float* h0  = (const float*)d_in[12];
  const float* c0  = (const float*)d_in[13];

  lstm_fused<<<dim3(2048/4), dim3(192), 0, stream>>>(
      adj, eps, Wi, bi, Wa, ba, Wp, bp, Wih, Whh, bih, bhh, h0, c0, (float*)d_out);
}